// Round 1
// baseline (164.113 us; speedup 1.0000x reference)
//
#include <hip/hip_runtime.h>

// ---------------------------------------------------------------------------
// SlidingWindowSelfAttention  (B=2, L=2048, D=1024, H=16, hd=64, WINDOW=256)
// R5: QKV GEMM -> 256x256 / BK=64 / 8-wave / 8-phase schedule (T2+T3+T4+T5)
//     with derived-wait counted vmcnt(8) (never 0 in main loop). Per-wave
//     output 128x64 (1.33x FLOP per LDS byte vs 64x64), st-swizzled LDS
//     (conflict-free ds_read_b128), setprio(1) around MFMA clusters.
//     attn / out-proj gemm / cast unchanged from R4.
// ---------------------------------------------------------------------------

#define SEQ_L 2048
#define WIN   256

typedef __bf16 bf16x8 __attribute__((ext_vector_type(8)));
typedef float  f32x4  __attribute__((ext_vector_type(4)));

template<int N> struct ic { static constexpr int v = N; };

__device__ __forceinline__ unsigned short f32_to_bf16(float f) {
  unsigned int u = __float_as_uint(f);
  u += 0x7FFFu + ((u >> 16) & 1u);      // round-to-nearest-even
  return (unsigned short)(u >> 16);
}

// async global->LDS, 16 B/lane; lds base must be wave-uniform (m104/m108)
__device__ __forceinline__ void async16(const unsigned short* g, unsigned short* l) {
  __builtin_amdgcn_global_load_lds(
      (const __attribute__((address_space(1))) unsigned int*)g,
      (__attribute__((address_space(3))) unsigned int*)l, 16, 0, 0);
}

// ---- fused fp32 -> bf16 cast for x, w1, w2 ----
__global__ void cast_all(const float* __restrict__ x,  unsigned short* __restrict__ xo,
                         const float* __restrict__ w1, unsigned short* __restrict__ w1o,
                         const float* __restrict__ w2, unsigned short* __restrict__ w2o) {
  int i = blockIdx.x * 256 + threadIdx.x;          // 2,097,152 float4 groups
  const float* in; unsigned short* out; int k;
  if (i < 1048576)       { in = x;  out = xo;  k = i; }
  else if (i < 1835008)  { in = w1; out = w1o; k = i - 1048576; }
  else                   { in = w2; out = w2o; k = i - 1835008; }
  float4 v = ((const float4*)in)[k];
  ushort4 o;
  o.x = f32_to_bf16(v.x); o.y = f32_to_bf16(v.y);
  o.z = f32_to_bf16(v.z); o.w = f32_to_bf16(v.w);
  ((ushort4*)out)[k] = o;
}

// ---------------------------------------------------------------------------
// C[M,N] = A[M,K] @ Bt[N,K]^T + bias, 256x256 tile, BK=64, 512 thr = 8 waves
// (2M x 4N), per-wave output 128x64. 8-phase schedule: per K-tile 4 quadrant
// phases (qm,qn); each phase: 12 ds_read_b128 || stage issue -> barrier ->
// lgkmcnt(0) -> setprio(1) 16 MFMA setprio(0) -> [counted vmcnt] -> barrier.
// Staging (derived waits, proven against buffer recycling):
//   q1(T): A1B1(T+1) -> buf^1   (A1/B1 regions of buf^1 freed at q4(T-1))
//   q3(T): A0(T+2)   -> buf     (A0 region of buf consumed after q2(T))
//   q4(T): B0(T+2)   -> buf     (B0 region of buf consumed after q3(T))
// => waits: vmcnt(8) at end-q1 (protects A1B1(T)), vmcnt(8) at end-q4
//    (protects A0B0(T+1)); tail peels to vmcnt(4)/vmcnt(0). Requires NT>=3,
//    M%256==0, N%256==0, K%64==0.
// LDS: 2 x (256x64) x 2 matrices x 2B = 128 KiB -> 1 block/CU.
// ---------------------------------------------------------------------------
template<int OUTBF>
__global__ __launch_bounds__(512, 2) void gemm_nt_256(
    const unsigned short* __restrict__ A,
    const unsigned short* __restrict__ Bt,
    const float* __restrict__ bias,
    void* __restrict__ Cout, int M, int N, int K)
{
  __shared__ unsigned short As[2][256 * 64];
  __shared__ unsigned short Bs[2][256 * 64];

  const int tid  = threadIdx.x;
  const int lane = tid & 63;
  const int w    = tid >> 6;          // 0..7
  const int wr   = w >> 2;            // 0..1  M-half of the block tile
  const int wc   = w & 3;             // 0..3  N-quarter
  const int quad = lane >> 4;
  const int l16  = lane & 15;
  const int lrow = lane >> 3 & 7;     // staging row-within-8
  const int scol = (lane & 7) ^ lrow; // swizzled source chunk (st-swizzle)

  const long m0 = (long)blockIdx.y * 256;
  const long n0 = (long)blockIdx.x * 256;

  f32x4 acc[8][4];
#pragma unroll
  for (int i = 0; i < 8; ++i)
#pragma unroll
    for (int j = 0; j < 4; ++j)
#pragma unroll
      for (int r = 0; r < 4; ++r) acc[i][j][r] = 0.0f;

  // ---- staging primitives: one instruction = 64 rows x 64 cols (8 KB) ----
  // A chunk: 64 contiguous tile rows at row0 (wave w stages rows row0+w*8..+7)
  auto stageA = [&](int buf, int row0, int kc) {
    async16(A + (m0 + row0 + w * 8 + lrow) * (long)K + kc + scol * 8,
            &As[buf][(row0 + w * 8) * 64]);
  };
  // B chunk: rows {b0..b0+31} u {b0+64..b0+95} (waves 0-3 / 4-7)
  auto stageB = [&](int buf, int b0, int kc) {
    int wrow = b0 + (w & 3) * 8 + (w >> 2) * 64;
    async16(Bt + (n0 + wrow + lrow) * (long)K + kc + scol * 8,
            &Bs[buf][wrow * 64]);
  };
  // halves (2 instructions each):
  auto hA0 = [&](int buf, int kc) { stageA(buf, 0,  kc); stageA(buf, 128, kc); };
  auto hA1 = [&](int buf, int kc) { stageA(buf, 64, kc); stageA(buf, 192, kc); };
  auto hB0 = [&](int buf, int kc) { stageB(buf, 0,  kc); stageB(buf, 128, kc); };
  auto hB1 = [&](int buf, int kc) { stageB(buf, 32, kc); stageB(buf, 160, kc); };

  auto vmw = [](auto n) {
    constexpr int V = decltype(n)::v;
    if constexpr (V == 8)      asm volatile("s_waitcnt vmcnt(8)" ::: "memory");
    else if constexpr (V == 4) asm volatile("s_waitcnt vmcnt(4)" ::: "memory");
    else if constexpr (V == 0) asm volatile("s_waitcnt vmcnt(0)" ::: "memory");
  };

  // ---- one quadrant phase ----
  auto phase = [&](int buf, auto qmc, auto qnc, auto stager, auto v) {
    constexpr int QM = decltype(qmc)::v, QN = decltype(qnc)::v;
    bf16x8 af[4][2], bq[2][2];
    const int rbase = wr * 128 + QM * 64;
#pragma unroll
    for (int mi = 0; mi < 4; ++mi) {
      const int rr = rbase + mi * 16 + l16;
#pragma unroll
      for (int kh = 0; kh < 2; ++kh)
        af[mi][kh] = *(const bf16x8*)&As[buf][rr * 64 + (((kh * 4 + quad) ^ (rr & 7)) << 3)];
    }
    const int cbase = wc * 64 + QN * 32;
#pragma unroll
    for (int ni = 0; ni < 2; ++ni) {
      const int rb = cbase + ni * 16 + l16;
#pragma unroll
      for (int kh = 0; kh < 2; ++kh)
        bq[ni][kh] = *(const bf16x8*)&Bs[buf][rb * 64 + (((kh * 4 + quad) ^ (rb & 7)) << 3)];
    }
    stager();
    asm volatile("s_waitcnt lgkmcnt(8)" ::: "memory");
    __builtin_amdgcn_s_barrier();
    asm volatile("s_waitcnt lgkmcnt(0)" ::: "memory");
    __builtin_amdgcn_sched_barrier(0);
    __builtin_amdgcn_s_setprio(1);
#pragma unroll
    for (int kh = 0; kh < 2; ++kh)
#pragma unroll
      for (int mi = 0; mi < 4; ++mi)
#pragma unroll
        for (int ni = 0; ni < 2; ++ni)
          acc[QM * 4 + mi][QN * 2 + ni] = __builtin_amdgcn_mfma_f32_16x16x32_bf16(
              af[mi][kh], bq[ni][kh], acc[QM * 4 + mi][QN * 2 + ni], 0, 0, 0);
    __builtin_amdgcn_s_setprio(0);
    vmw(v);
    __builtin_amdgcn_s_barrier();
  };

  // ---- one K-tile = 4 quadrant phases ----
  auto tile = [&](int T, auto s1, auto s34, auto v1, auto v4) {
    const int buf = T & 1;
    const int kn1 = (T + 1) << 6;
    const int kn2 = (T + 2) << 6;
    phase(buf, ic<0>{}, ic<0>{},
          [&] { if constexpr (decltype(s1)::v) { hA1(buf ^ 1, kn1); hB1(buf ^ 1, kn1); } }, v1);
    phase(buf, ic<0>{}, ic<1>{}, [&] {}, ic<-1>{});
    phase(buf, ic<1>{}, ic<0>{},
          [&] { if constexpr (decltype(s34)::v) hA0(buf, kn2); }, ic<-1>{});
    phase(buf, ic<1>{}, ic<1>{},
          [&] { if constexpr (decltype(s34)::v) hB0(buf, kn2); }, v4);
  };

  // ---- prologue: issue order mimics steady-state stream ----
  // [A0(0) B0(0)] [A1B1(0)] [A0(1) B0(1)]  = 12 loads
  hA0(0, 0); hB0(0, 0); hA1(0, 0); hB1(0, 0); hA0(1, 64); hB0(1, 64);
  asm volatile("s_waitcnt vmcnt(8)" ::: "memory");   // A0(0),B0(0) landed
  __builtin_amdgcn_s_barrier();

  const int NT = K >> 6;                             // requires NT >= 3
  int T = 0;
#pragma unroll 1
  for (; T < NT - 2; ++T)
    tile(T, ic<1>{}, ic<1>{}, ic<8>{}, ic<8>{});
  tile(NT - 2, ic<1>{}, ic<0>{}, ic<8>{}, ic<4>{});
  tile(NT - 1, ic<0>{}, ic<0>{}, ic<0>{}, ic<-1>{});

  // ---- epilogue ----
#pragma unroll
  for (int qn = 0; qn < 2; ++qn)
#pragma unroll
    for (int ni = 0; ni < 2; ++ni) {
      long col = n0 + wc * 64 + qn * 32 + ni * 16 + l16;
      float bv = bias[col];
#pragma unroll
      for (int qm = 0; qm < 2; ++qm)
#pragma unroll
        for (int mi = 0; mi < 4; ++mi) {
          long rowb = m0 + wr * 128 + qm * 64 + mi * 16 + quad * 4;
#pragma unroll
          for (int r = 0; r < 4; ++r) {
            float v = acc[qm * 4 + mi][qn * 2 + ni][r] + bv;
            if (OUTBF) ((unsigned short*)Cout)[(rowb + r) * N + col] = f32_to_bf16(v);
            else       ((float*)Cout)[(rowb + r) * N + col] = v;
          }
        }
    }
}

// ---------------------------------------------------------------------------
// C[M,N] = A[M,K] @ Bt[N,K]^T + bias   (bf16 in, fp32 accum), m97 structure.
// Kept for the out-projection (64x64 tile, 1024 blocks = 4/CU).
// ---------------------------------------------------------------------------
template<int TBM, int TBN, int MI, int NI, int OUTBF>
__global__ __launch_bounds__(256) void gemm_nt(
    const unsigned short* __restrict__ A,
    const unsigned short* __restrict__ Bt,
    const float* __restrict__ bias,
    void* __restrict__ Cout, int M, int N, int K)
{
  __shared__ unsigned short As[TBM * 64];
  __shared__ unsigned short Bs[TBN * 64];

  const int tid  = threadIdx.x;
  const int lane = tid & 63;
  const int wave = tid >> 6;
  const int wr   = (wave >> 1) * (MI * 16);
  const int wc   = (wave & 1) * (NI * 16);
  const int quad = lane >> 4;
  const int l16  = lane & 15;
  const int lrow = lane >> 3;            // staging row-within-8
  const int scol = (lane & 7) ^ lrow;    // swizzled source chunk

  const long m0 = (long)blockIdx.y * TBM;
  const long n0 = (long)blockIdx.x * TBN;

  f32x4 acc[MI][NI];
#pragma unroll
  for (int i = 0; i < MI; ++i)
#pragma unroll
    for (int j = 0; j < NI; ++j)
#pragma unroll
      for (int r = 0; r < 4; ++r) acc[i][j][r] = 0.0f;

  for (int k0 = 0; k0 < K; k0 += 64) {
#pragma unroll
    for (int p = 0; p < TBM / 32; ++p) {
      int rb = wave * (TBM / 4) + p * 8;
      async16(A + (m0 + rb + lrow) * (long)K + k0 + scol * 8, &As[rb * 64]);
    }
#pragma unroll
    for (int p = 0; p < TBN / 32; ++p) {
      int rb = wave * (TBN / 4) + p * 8;
      async16(Bt + (n0 + rb + lrow) * (long)K + k0 + scol * 8, &Bs[rb * 64]);
    }
    __syncthreads();
#pragma unroll
    for (int ks = 0; ks < 2; ++ks) {
      bf16x8 af[MI], bfv[NI];
#pragma unroll
      for (int mi = 0; mi < MI; ++mi) {
        int r = wr + mi * 16 + l16;
        af[mi] = *(const bf16x8*)(&As[r * 64 + ((ks * 4 + quad) ^ (r & 7)) * 8]);
      }
#pragma unroll
      for (int ni = 0; ni < NI; ++ni) {
        int r = wc + ni * 16 + l16;
        bfv[ni] = *(const bf16x8*)(&Bs[r * 64 + ((ks * 4 + quad) ^ (r & 7)) * 8]);
      }
#pragma unroll
      for (int mi = 0; mi < MI; ++mi)
#pragma unroll
        for (int ni = 0; ni < NI; ++ni)
          acc[mi][ni] = __builtin_amdgcn_mfma_f32_16x16x32_bf16(af[mi], bfv[ni], acc[mi][ni], 0, 0, 0);
    }
    __syncthreads();
  }

#pragma unroll
  for (int ni = 0; ni < NI; ++ni) {
    long col = n0 + wc + ni * 16 + l16;
    float bv = bias[col];
#pragma unroll
    for (int mi = 0; mi < MI; ++mi) {
      long rowb = m0 + wr + mi * 16 + quad * 4;
#pragma unroll
      for (int r = 0; r < 4; ++r) {
        float v = acc[mi][ni][r] + bv;
        if (OUTBF) ((unsigned short*)Cout)[(rowb + r) * N + col] = f32_to_bf16(v);
        else       ((float*)Cout)[(rowb + r) * N + col] = v;
      }
    }
  }
}

// ---------------------------------------------------------------------------
// Windowed flash attention, no-max softmax, 128 queries/block. (unchanged R4)
// ---------------------------------------------------------------------------
__global__ __launch_bounds__(256) void attn_kernel(
    const unsigned short* __restrict__ qkv,
    unsigned short* __restrict__ aout)
{
  __shared__ unsigned short Ks[64 * 72];       // [key][d]
  __shared__ unsigned short Vt[64 * 72];       // [d][key^swz]
  __shared__ unsigned short Ps[4 * 16 * 72];   // per-wave [q][key]

  const int tid  = threadIdx.x;
  const int w    = tid >> 6;
  const int lane = tid & 63;
  const int quad = lane >> 4;
  const int l16  = lane & 15;

  const int blk = blockIdx.x;            // 512 = b(2) * h(16) * 16 q-blocks
  const int qb  = blk & 15;
  const int h   = (blk >> 4) & 15;
  const int b   = blk >> 8;

  const int  i0 = qb * 128;
  const long rowbase = (long)b * SEQ_L;

  // Q fragments for both subtiles: A[m=l16][k=quad*8+j] (+32)
  bf16x8 aq[2][2];
#pragma unroll
  for (int sub = 0; sub < 2; ++sub) {
    const unsigned short* qp =
        qkv + (rowbase + i0 + sub * 64 + w * 16 + l16) * 3072 + h * 64 + quad * 8;
    aq[sub][0] = *(const bf16x8*)(qp);
    aq[sub][1] = *(const bf16x8*)(qp + 32);
  }

  f32x4 o[2][4];
  float l_i[2][4];
#pragma unroll
  for (int sub = 0; sub < 2; ++sub)
#pragma unroll
    for (int ni = 0; ni < 4; ++ni)
#pragma unroll
      for (int r = 0; r < 4; ++r) { o[sub][ni][r] = 0.0f; l_i[sub][r] = 0.0f; }

  unsigned short* psw = &Ps[w * 16 * 72];

  const int j_begin = (i0 >= WIN) ? i0 - WIN : 0;

  for (int j0 = j_begin; j0 < i0 + 128; j0 += 64) {
    __syncthreads();   // previous tile's Ks/Vt reads done
    // ---- stage K tile + transposed V tile ----
#pragma unroll
    for (int p = 0; p < 2; ++p) {
      int c = p * 256 + tid, row = c >> 3, col8 = c & 7;
      const unsigned short* base = qkv + (rowbase + j0 + row) * 3072 + h * 64 + col8 * 8;
      *(uint4*)(&Ks[row * 72 + col8 * 8]) = *(const uint4*)(base + 1024);
      unsigned short tmp[8];
      *(uint4*)tmp = *(const uint4*)(base + 2048);
      int rsw = row ^ (col8 << 3);
#pragma unroll
      for (int e = 0; e < 8; ++e)
        Vt[(col8 * 8 + e) * 72 + rsw] = tmp[e];
    }
    __syncthreads();

    // ---- hoist K and V fragments (shared by both subtiles) ----
    bf16x8 kf[4][2];
#pragma unroll
    for (int g = 0; g < 4; ++g) {
      kf[g][0] = *(const bf16x8*)(&Ks[(g * 16 + l16) * 72 + quad * 8]);
      kf[g][1] = *(const bf16x8*)(&Ks[(g * 16 + l16) * 72 + 32 + quad * 8]);
    }
    bf16x8 vf[2][4];
#pragma unroll
    for (int kk = 0; kk < 2; ++kk)
#pragma unroll
      for (int ni = 0; ni < 4; ++ni) {
        int d  = ni * 16 + l16;
        int rb = (kk * 32 + quad * 8) ^ (((d >> 3) & 7) << 3);
        vf[kk][ni] = *(const bf16x8*)(&Vt[d * 72 + rb]);
      }

#pragma unroll
    for (int sub = 0; sub < 2; ++sub) {
      const int i0s = i0 + sub * 64 + w * 16;
      if (j0 > i0s + 15) continue;              // entirely in the future
      if (j0 + 63 + WIN <= i0s) continue;       // entirely before the window

      // ---- S = Q.K^T ----
      f32x4 s[4];
#pragma unroll
      for (int g = 0; g < 4; ++g) {
        f32x4 z;
#pragma unroll
        for (int r = 0; r < 4; ++r) z[r] = 0.0f;
        z = __builtin_amdgcn_mfma_f32_16x16x32_bf16(aq[sub][0], kf[g][0], z, 0, 0, 0);
        z = __builtin_amdgcn_mfma_f32_16x16x32_bf16(aq[sub][1], kf[g][1], z, 0, 0, 0);
        s[g] = z;
      }
      // ---- mask + exp (no max subtraction) + P write + local l ----
#pragma unroll
      for (int g = 0; g < 4; ++g) {
        int j = j0 + g * 16 + l16;
#pragma unroll
        for (int r = 0; r < 4; ++r) {
          int i = i0s + quad * 4 + r;
          bool ok = (j <= i) && (j > i - WIN);
          float e = ok ? __expf(s[g][r] * 0.125f) : 0.0f;
          psw[(quad * 4 + r) * 72 + g * 16 + l16] = f32_to_bf16(e);
          l_i[sub][r] += e;
        }
      }
      asm volatile("s_waitcnt lgkmcnt(0)" ::: "memory");  // P visible to own wave
      // ---- O += P.V ----
#pragma unroll
      for (int kk = 0; kk < 2; ++kk) {
        bf16x8 ap = *(const bf16x8*)(&psw[l16 * 72 + kk * 32 + quad * 8]);
#pragma unroll
        for (int ni = 0; ni < 4; ++ni)
          o[sub][ni] = __builtin_amdgcn_mfma_f32_16x16x32_bf16(ap, vf[kk][ni], o[sub][ni], 0, 0, 0);
      }
    }
  }

  // ---- epilogue: one l-reduction, normalize, store bf16 [token][h*64+d] ----
#pragma unroll
  for (int sub = 0; sub < 2; ++sub)
#pragma unroll
    for (int r = 0; r < 4; ++r) {
      float rs = l_i[sub][r];
      rs += __shfl_xor(rs, 1);
      rs += __shfl_xor(rs, 2);
      rs += __shfl_xor(rs, 4);
      rs += __shfl_xor(rs, 8);
      float inv_l = 1.0f / rs;
      long row = rowbase + i0 + sub * 64 + w * 16 + quad * 4 + r;
#pragma unroll
      for (int ni = 0; ni < 4; ++ni)
        aout[row * 1024 + h * 64 + ni * 16 + l16] = f32_to_bf16(o[sub][ni][r] * inv_l);
    }
}

// ---------------------------------------------------------------------------
extern "C" void kernel_launch(void* const* d_in, const int* in_sizes, int n_in,
                              void* d_out, int out_size, void* d_ws, size_t ws_size,
                              hipStream_t stream)
{
  const float* x  = (const float*)d_in[0];   // [2,2048,1024]
  const float* w1 = (const float*)d_in[1];   // [3072,1024]
  const float* b1 = (const float*)d_in[2];   // [3072]
  const float* w2 = (const float*)d_in[3];   // [1024,1024]
  const float* b2 = (const float*)d_in[4];   // [1024]
  float* out = (float*)d_out;                // [2,2048,1024] fp32

  char* ws = (char*)d_ws;
  unsigned short* x_bf   = (unsigned short*)(ws);              //  8.39 MB
  unsigned short* w1_bf  = (unsigned short*)(ws + 8388608);    //  6.29 MB
  unsigned short* w2_bf  = (unsigned short*)(ws + 14680064);   //  2.10 MB
  unsigned short* qkv_bf = (unsigned short*)(ws + 16777216);   // 25.17 MB
  unsigned short* at_bf  = (unsigned short*)(ws + 41943040);   //  8.39 MB

  cast_all<<<8192, 256, 0, stream>>>(x, x_bf, w1, w1_bf, w2, w2_bf);

  dim3 g1(3072 / 256, 4096 / 256);   // (12, 16) = 192 blocks, 512 thr
  gemm_nt_256<1><<<g1, 512, 0, stream>>>(x_bf, w1_bf, b1, qkv_bf, 4096, 3072, 1024);

  attn_kernel<<<512, 256, 0, stream>>>(qkv_bf, at_bf);

  dim3 g2(1024 / 64, 4096 / 64);     // (16, 64) = 1024 blocks
  gemm_nt<64, 64, 2, 2, 0><<<g2, 256, 0, stream>>>(at_bf, w2_bf, b2, out, 4096, 1024, 1024);
}

// Round 3
// 154.943 us; speedup vs baseline: 1.0592x; 1.0592x over previous
//
#include <hip/hip_runtime.h>

// ---------------------------------------------------------------------------
// SlidingWindowSelfAttention  (B=2, L=2048, D=1024, H=16, hd=64, WINDOW=256)
// R7 = R6 resubmission (R6 container failure was infra-side; OOB/hang/ledger
//     re-audit found no kernel defect — see journal):
//     QKV GEMM: 256x192 tile (grid 16x16 = 256 blocks, 100% CU coverage),
//     minimal-LDS-read phases (22 ds_read_b128/wave/tile: B-frags held across
//     the QM phase pair), 3 barriers/tile, counted vmcnt(7) (never 0 in main
//     loop), swapped-operand MFMA -> ushort4 epilogue stores.
//     attn / out-proj gemm / cast unchanged.
// ---------------------------------------------------------------------------

#define SEQ_L 2048
#define WIN   256

typedef __bf16 bf16x8 __attribute__((ext_vector_type(8)));
typedef float  f32x4  __attribute__((ext_vector_type(4)));

template<int X> struct ic { static constexpr int v = X; };

__device__ __forceinline__ unsigned short f32_to_bf16(float f) {
  unsigned int u = __float_as_uint(f);
  u += 0x7FFFu + ((u >> 16) & 1u);      // round-to-nearest-even
  return (unsigned short)(u >> 16);
}

// async global->LDS, 16 B/lane; lds base must be wave-uniform (m104/m108)
__device__ __forceinline__ void async16(const unsigned short* g, unsigned short* l) {
  __builtin_amdgcn_global_load_lds(
      (const __attribute__((address_space(1))) unsigned int*)g,
      (__attribute__((address_space(3))) unsigned int*)l, 16, 0, 0);
}

// ---- fused fp32 -> bf16 cast for x, w1, w2 ----
__global__ void cast_all(const float* __restrict__ x,  unsigned short* __restrict__ xo,
                         const float* __restrict__ w1, unsigned short* __restrict__ w1o,
                         const float* __restrict__ w2, unsigned short* __restrict__ w2o) {
  int i = blockIdx.x * 256 + threadIdx.x;          // 2,097,152 float4 groups
  const float* in; unsigned short* out; int k;
  if (i < 1048576)       { in = x;  out = xo;  k = i; }
  else if (i < 1835008)  { in = w1; out = w1o; k = i - 1048576; }
  else                   { in = w2; out = w2o; k = i - 1835008; }
  float4 v = ((const float4*)in)[k];
  ushort4 o;
  o.x = f32_to_bf16(v.x); o.y = f32_to_bf16(v.y);
  o.z = f32_to_bf16(v.z); o.w = f32_to_bf16(v.w);
  ((ushort4*)out)[k] = o;
}

// ---------------------------------------------------------------------------
// QKV GEMM: C[4096,3072] = A[4096,1024] @ Bt[3072,1024]^T + bias, bf16 out.
// 256x192 tile, BK=64, 512 thr = 8 waves (2M x 4N), per-wave 128x48.
// Phases per K-tile (QM, kh): p1=(0,kh0) p2=(1,kh0) p3=(0,kh1) p4=(1,kh1).
// Reads: af (4/phase, fresh), bq (3, read at p1/p3, HELD across the QM pair)
// => 22 ds_read_b128 / wave / tile (minimal).  MFMA: 12/phase (operands
// SWAPPED: mfma(bq, af, acc) so each thread's f32x4 = 4 consecutive C-cols
// of one row -> ushort4 epilogue stores).
// Staging per tile: p1 issues A1(T+1)->buf^1 (legal: last read of A1(T-1) is
// p4(T-1), lgkmcnt(0)'d + barrier'd); p4 issues A0(T+2)+B(T+2)->buf (legal:
// last reads of A0(T)/B(T) are p3(T), barrier'd at end-p3).
// Per-wave vmcnt ledger (each wave stages its own 8-row slices; pre-barrier
// vmcnt publishes its slice, barrier publishes all): steady outstanding after
// end-p4 = A1(T+1)[2]+A0(T+2)[2]+B(T+2)[3] = 7.  end-p1: issue 2 -> vmcnt(7)
// retires exactly A1(T) (read at p2).  end-p4: issue 5 -> vmcnt(7) retires
// exactly A0B(T+1) (read at p1(T+1)).  Tail peels 7 -> 2 -> 0.
// Barriers: end-p1, end-p3, end-p4 only (p2->p3 has no cross-wave hazard).
// LDS: (256+192)*64*2B*2buf = 112 KiB -> 1 block/CU. Requires NT >= 3.
// ---------------------------------------------------------------------------
__global__ __launch_bounds__(512, 2) void gemm_qkv(
    const unsigned short* __restrict__ A,
    const unsigned short* __restrict__ Bt,
    const float* __restrict__ bias,
    unsigned short* __restrict__ C, int M, int N, int K)
{
  __shared__ unsigned short As[2][256 * 64];
  __shared__ unsigned short Bs[2][192 * 64];

  const int tid  = threadIdx.x;
  const int lane = tid & 63;
  const int w    = tid >> 6;          // 0..7
  const int wr   = w >> 2;            // 0..1  M-half
  const int wc   = w & 3;             // 0..3  N-quarter (48 cols each)
  const int quad = lane >> 4;
  const int l16  = lane & 15;
  const int lrow = (lane >> 3) & 7;   // staging row-within-8
  const int scol = (lane & 7) ^ lrow; // swizzled source chunk (st-swizzle)

  const long m0 = (long)blockIdx.y * 256;
  const long n0 = (long)blockIdx.x * 192;

  f32x4 acc[8][3];
#pragma unroll
  for (int i = 0; i < 8; ++i)
#pragma unroll
    for (int j = 0; j < 3; ++j)
#pragma unroll
      for (int r = 0; r < 4; ++r) acc[i][j][r] = 0.0f;

  // ---- staging: one async16 = 64 rows x 64 cols (8 KB), wave w rows w*8..+7
  auto stA = [&](int buf, int c, int kc) {
    async16(A + (m0 + c * 64 + w * 8 + lrow) * (long)K + kc + scol * 8,
            &As[buf][(c * 64 + w * 8) * 64]);
  };
  auto stB = [&](int buf, int c, int kc) {
    async16(Bt + (n0 + c * 64 + w * 8 + lrow) * (long)K + kc + scol * 8,
            &Bs[buf][(c * 64 + w * 8) * 64]);
  };
  auto hA0 = [&](int buf, int kc) { stA(buf, 0, kc); stA(buf, 2, kc); }; // rows 0-63,128-191
  auto hA1 = [&](int buf, int kc) { stA(buf, 1, kc); stA(buf, 3, kc); }; // rows 64-127,192-255
  auto hB  = [&](int buf, int kc) { stB(buf, 0, kc); stB(buf, 1, kc); stB(buf, 2, kc); };

  // ---- fragment reads (swizzled, conflict-free: verified R3/R5) ----
  auto rdA = [&](bf16x8 (&af)[4], int buf, int QM, int kh) {
#pragma unroll
    for (int mi = 0; mi < 4; ++mi) {
      int rr = wr * 128 + QM * 64 + mi * 16 + l16;
      af[mi] = *(const bf16x8*)&As[buf][rr * 64 + (((kh * 4 + quad) ^ (rr & 7)) << 3)];
    }
  };
  auto rdB = [&](bf16x8 (&bq)[3], int buf, int kh) {
#pragma unroll
    for (int ni = 0; ni < 3; ++ni) {
      int rb = wc * 48 + ni * 16 + l16;
      bq[ni] = *(const bf16x8*)&Bs[buf][rb * 64 + (((kh * 4 + quad) ^ (rb & 7)) << 3)];
    }
  };
  // operand-swapped: D "row"(quad,reg) axis = bq's index (C-col),
  // D "col"(l16) axis = af's index (C-row) -> thread holds 4 consecutive cols.
  auto cluster = [&](bf16x8 (&af)[4], bf16x8 (&bq)[3], int mb) {
    __builtin_amdgcn_s_setprio(1);
#pragma unroll
    for (int mi = 0; mi < 4; ++mi)
#pragma unroll
      for (int ni = 0; ni < 3; ++ni)
        acc[mb + mi][ni] = __builtin_amdgcn_mfma_f32_16x16x32_bf16(
            bq[ni], af[mi], acc[mb + mi][ni], 0, 0, 0);
    __builtin_amdgcn_s_setprio(0);
  };
  auto lgkm0 = [] {
    asm volatile("s_waitcnt lgkmcnt(0)" ::: "memory");
    __builtin_amdgcn_sched_barrier(0);   // rule 18: pin MFMA after the wait
  };
  auto vmw = [](auto n) {
    constexpr int V = decltype(n)::v;
    if constexpr (V == 7)      asm volatile("s_waitcnt vmcnt(7)" ::: "memory");
    else if constexpr (V == 2) asm volatile("s_waitcnt vmcnt(2)" ::: "memory");
    else if constexpr (V == 0) asm volatile("s_waitcnt vmcnt(0)" ::: "memory");
  };

  // ---- prologue: [A0(0) B(0)] [A1(0)] [A0(1) B(1)] = 12 loads ----
  hA0(0, 0); hB(0, 0); hA1(0, 0); hA0(1, 64); hB(1, 64);
  asm volatile("s_waitcnt vmcnt(7)" ::: "memory");   // A0(0),B(0) landed
  __builtin_amdgcn_s_barrier();

  auto tile = [&](int T, auto s1, auto s4, auto v1, auto v4) {
    const int buf = T & 1;
    bf16x8 af[4], bq0[3], bq1[3];
    // ---- p1 (QM0, kh0) + issue A1(T+1) ----
    rdA(af, buf, 0, 0);
    rdB(bq0, buf, 0);
    if constexpr (decltype(s1)::v) hA1(buf ^ 1, (T + 1) * 64);
    lgkm0();
    cluster(af, bq0, 0);
    vmw(v1);
    __builtin_amdgcn_s_barrier();
    // ---- p2 (QM1, kh0): bq0 held ----
    rdA(af, buf, 1, 0);
    lgkm0();
    cluster(af, bq0, 4);
    // ---- p3 (QM0, kh1): no barrier before (no cross-wave hazard) ----
    rdA(af, buf, 0, 1);
    rdB(bq1, buf, 1);
    lgkm0();
    cluster(af, bq1, 0);
    __builtin_amdgcn_s_barrier();      // last consumers of A0(T)/B(T) done
    // ---- p4 (QM1, kh1) + issue A0(T+2), B(T+2) ----
    rdA(af, buf, 1, 1);
    if constexpr (decltype(s4)::v) { hA0(buf, (T + 2) * 64); hB(buf, (T + 2) * 64); }
    lgkm0();
    cluster(af, bq1, 4);
    vmw(v4);
    __builtin_amdgcn_s_barrier();
  };

  const int NT = K >> 6;               // 16; requires NT >= 3
#pragma unroll 1
  for (int T = 0; T < NT - 2; ++T) tile(T, ic<1>{}, ic<1>{}, ic<7>{}, ic<7>{});
  tile(NT - 2, ic<1>{}, ic<0>{}, ic<7>{}, ic<2>{});
  tile(NT - 1, ic<0>{}, ic<0>{}, ic<0>{}, ic<-1>{});

  // ---- epilogue: thread (quad,l16) holds C[m][nb..nb+3] -> ushort4 store ---
#pragma unroll
  for (int ni = 0; ni < 3; ++ni) {
    const int nb = wc * 48 + ni * 16 + quad * 4;
    const float4 bv = *(const float4*)&bias[n0 + nb];
#pragma unroll
    for (int qm = 0; qm < 2; ++qm)
#pragma unroll
      for (int mi = 0; mi < 4; ++mi) {
        long m = m0 + wr * 128 + qm * 64 + mi * 16 + l16;
        f32x4 a = acc[qm * 4 + mi][ni];
        ushort4 o;
        o.x = f32_to_bf16(a[0] + bv.x);
        o.y = f32_to_bf16(a[1] + bv.y);
        o.z = f32_to_bf16(a[2] + bv.z);
        o.w = f32_to_bf16(a[3] + bv.w);
        *(ushort4*)&C[m * (long)N + n0 + nb] = o;
      }
  }
}

// ---------------------------------------------------------------------------
// C[M,N] = A[M,K] @ Bt[N,K]^T + bias   (bf16 in, fp32 accum), m97 structure.
// Kept for the out-projection (64x64 tile, 1024 blocks = 4/CU).
// ---------------------------------------------------------------------------
template<int TBM, int TBN, int MI, int NI, int OUTBF>
__global__ __launch_bounds__(256) void gemm_nt(
    const unsigned short* __restrict__ A,
    const unsigned short* __restrict__ Bt,
    const float* __restrict__ bias,
    void* __restrict__ Cout, int M, int N, int K)
{
  __shared__ unsigned short As[TBM * 64];
  __shared__ unsigned short Bs[TBN * 64];

  const int tid  = threadIdx.x;
  const int lane = tid & 63;
  const int wave = tid >> 6;
  const int wr   = (wave >> 1) * (MI * 16);
  const int wc   = (wave & 1) * (NI * 16);
  const int quad = lane >> 4;
  const int l16  = lane & 15;
  const int lrow = lane >> 3;            // staging row-within-8
  const int scol = (lane & 7) ^ lrow;    // swizzled source chunk

  const long m0 = (long)blockIdx.y * TBM;
  const long n0 = (long)blockIdx.x * TBN;

  f32x4 acc[MI][NI];
#pragma unroll
  for (int i = 0; i < MI; ++i)
#pragma unroll
    for (int j = 0; j < NI; ++j)
#pragma unroll
      for (int r = 0; r < 4; ++r) acc[i][j][r] = 0.0f;

  for (int k0 = 0; k0 < K; k0 += 64) {
#pragma unroll
    for (int p = 0; p < TBM / 32; ++p) {
      int rb = wave * (TBM / 4) + p * 8;
      async16(A + (m0 + rb + lrow) * (long)K + k0 + scol * 8, &As[rb * 64]);
    }
#pragma unroll
    for (int p = 0; p < TBN / 32; ++p) {
      int rb = wave * (TBN / 4) + p * 8;
      async16(Bt + (n0 + rb + lrow) * (long)K + k0 + scol * 8, &Bs[rb * 64]);
    }
    __syncthreads();
#pragma unroll
    for (int ks = 0; ks < 2; ++ks) {
      bf16x8 af[MI], bfv[NI];
#pragma unroll
      for (int mi = 0; mi < MI; ++mi) {
        int r = wr + mi * 16 + l16;
        af[mi] = *(const bf16x8*)(&As[r * 64 + ((ks * 4 + quad) ^ (r & 7)) * 8]);
      }
#pragma unroll
      for (int ni = 0; ni < NI; ++ni) {
        int r = wc + ni * 16 + l16;
        bfv[ni] = *(const bf16x8*)(&Bs[r * 64 + ((ks * 4 + quad) ^ (r & 7)) * 8]);
      }
#pragma unroll
      for (int mi = 0; mi < MI; ++mi)
#pragma unroll
        for (int ni = 0; ni < NI; ++ni)
          acc[mi][ni] = __builtin_amdgcn_mfma_f32_16x16x32_bf16(af[mi], bfv[ni], acc[mi][ni], 0, 0, 0);
    }
    __syncthreads();
  }

#pragma unroll
  for (int ni = 0; ni < NI; ++ni) {
    long col = n0 + wc + ni * 16 + l16;
    float bv = bias[col];
#pragma unroll
    for (int mi = 0; mi < MI; ++mi) {
      long rowb = m0 + wr + mi * 16 + quad * 4;
#pragma unroll
      for (int r = 0; r < 4; ++r) {
        float v = acc[mi][ni][r] + bv;
        if (OUTBF) ((unsigned short*)Cout)[(rowb + r) * N + col] = f32_to_bf16(v);
        else       ((float*)Cout)[(rowb + r) * N + col] = v;
      }
    }
  }
}

// ---------------------------------------------------------------------------
// Windowed flash attention, no-max softmax, 128 queries/block. (unchanged)
// ---------------------------------------------------------------------------
__global__ __launch_bounds__(256) void attn_kernel(
    const unsigned short* __restrict__ qkv,
    unsigned short* __restrict__ aout)
{
  __shared__ unsigned short Ks[64 * 72];       // [key][d]
  __shared__ unsigned short Vt[64 * 72];       // [d][key^swz]
  __shared__ unsigned short Ps[4 * 16 * 72];   // per-wave [q][key]

  const int tid  = threadIdx.x;
  const int w    = tid >> 6;
  const int lane = tid & 63;
  const int quad = lane >> 4;
  const int l16  = lane & 15;

  const int blk = blockIdx.x;            // 512 = b(2) * h(16) * 16 q-blocks
  const int qb  = blk & 15;
  const int h   = (blk >> 4) & 15;
  const int b   = blk >> 8;

  const int  i0 = qb * 128;
  const long rowbase = (long)b * SEQ_L;

  // Q fragments for both subtiles: A[m=l16][k=quad*8+j] (+32)
  bf16x8 aq[2][2];
#pragma unroll
  for (int sub = 0; sub < 2; ++sub) {
    const unsigned short* qp =
        qkv + (rowbase + i0 + sub * 64 + w * 16 + l16) * 3072 + h * 64 + quad * 8;
    aq[sub][0] = *(const bf16x8*)(qp);
    aq[sub][1] = *(const bf16x8*)(qp + 32);
  }

  f32x4 o[2][4];
  float l_i[2][4];
#pragma unroll
  for (int sub = 0; sub < 2; ++sub)
#pragma unroll
    for (int ni = 0; ni < 4; ++ni)
#pragma unroll
      for (int r = 0; r < 4; ++r) { o[sub][ni][r] = 0.0f; l_i[sub][r] = 0.0f; }

  unsigned short* psw = &Ps[w * 16 * 72];

  const int j_begin = (i0 >= WIN) ? i0 - WIN : 0;

  for (int j0 = j_begin; j0 < i0 + 128; j0 += 64) {
    __syncthreads();   // previous tile's Ks/Vt reads done
    // ---- stage K tile + transposed V tile ----
#pragma unroll
    for (int p = 0; p < 2; ++p) {
      int c = p * 256 + tid, row = c >> 3, col8 = c & 7;
      const unsigned short* base = qkv + (rowbase + j0 + row) * 3072 + h * 64 + col8 * 8;
      *(uint4*)(&Ks[row * 72 + col8 * 8]) = *(const uint4*)(base + 1024);
      unsigned short tmp[8];
      *(uint4*)tmp = *(const uint4*)(base + 2048);
      int rsw = row ^ (col8 << 3);
#pragma unroll
      for (int e = 0; e < 8; ++e)
        Vt[(col8 * 8 + e) * 72 + rsw] = tmp[e];
    }
    __syncthreads();

    // ---- hoist K and V fragments (shared by both subtiles) ----
    bf16x8 kf[4][2];
#pragma unroll
    for (int g = 0; g < 4; ++g) {
      kf[g][0] = *(const bf16x8*)(&Ks[(g * 16 + l16) * 72 + quad * 8]);
      kf[g][1] = *(const bf16x8*)(&Ks[(g * 16 + l16) * 72 + 32 + quad * 8]);
    }
    bf16x8 vf[2][4];
#pragma unroll
    for (int kk = 0; kk < 2; ++kk)
#pragma unroll
      for (int ni = 0; ni < 4; ++ni) {
        int d  = ni * 16 + l16;
        int rb = (kk * 32 + quad * 8) ^ (((d >> 3) & 7) << 3);
        vf[kk][ni] = *(const bf16x8*)(&Vt[d * 72 + rb]);
      }

#pragma unroll
    for (int sub = 0; sub < 2; ++sub) {
      const int i0s = i0 + sub * 64 + w * 16;
      if (j0 > i0s + 15) continue;              // entirely in the future
      if (j0 + 63 + WIN <= i0s) continue;       // entirely before the window

      // ---- S = Q.K^T ----
      f32x4 s[4];
#pragma unroll
      for (int g = 0; g < 4; ++g) {
        f32x4 z;
#pragma unroll
        for (int r = 0; r < 4; ++r) z[r] = 0.0f;
        z = __builtin_amdgcn_mfma_f32_16x16x32_bf16(aq[sub][0], kf[g][0], z, 0, 0, 0);
        z = __builtin_amdgcn_mfma_f32_16x16x32_bf16(aq[sub][1], kf[g][1], z, 0, 0, 0);
        s[g] = z;
      }
      // ---- mask + exp (no max subtraction) + P write + local l ----
#pragma unroll
      for (int g = 0; g < 4; ++g) {
        int j = j0 + g * 16 + l16;
#pragma unroll
        for (int r = 0; r < 4; ++r) {
          int i = i0s + quad * 4 + r;
          bool ok = (j <= i) && (j > i - WIN);
          float e = ok ? __expf(s[g][r] * 0.125f) : 0.0f;
          psw[(quad * 4 + r) * 72 + g * 16 + l16] = f32_to_bf16(e);
          l_i[sub][r] += e;
        }
      }
      asm volatile("s_waitcnt lgkmcnt(0)" ::: "memory");  // P visible to own wave
      // ---- O += P.V ----
#pragma unroll
      for (int kk = 0; kk < 2; ++kk) {
        bf16x8 ap = *(const bf16x8*)(&psw[l16 * 72 + kk * 32 + quad * 8]);
#pragma unroll
        for (int ni = 0; ni < 4; ++ni)
          o[sub][ni] = __builtin_amdgcn_mfma_f32_16x16x32_bf16(ap, vf[kk][ni], o[sub][ni], 0, 0, 0);
      }
    }
  }

  // ---- epilogue: one l-reduction, normalize, store bf16 [token][h*64+d] ----
#pragma unroll
  for (int sub = 0; sub < 2; ++sub)
#pragma unroll
    for (int r = 0; r < 4; ++r) {
      float rs = l_i[sub][r];
      rs += __shfl_xor(rs, 1);
      rs += __shfl_xor(rs, 2);
      rs += __shfl_xor(rs, 4);
      rs += __shfl_xor(rs, 8);
      float inv_l = 1.0f / rs;
      long row = rowbase + i0 + sub * 64 + w * 16 + quad * 4 + r;
#pragma unroll
      for (int ni = 0; ni < 4; ++ni)
        aout[row * 1024 + h * 64 + ni * 16 + l16] = f32_to_bf16(o[sub][ni][r] * inv_l);
    }
}

// ---------------------------------------------------------------------------
extern "C" void kernel_launch(void* const* d_in, const int* in_sizes, int n_in,
                              void* d_out, int out_size, void* d_ws, size_t ws_size,
                              hipStream_t stream)
{
  const float* x  = (const float*)d_in[0];   // [2,2048,1024]
  const float* w1 = (const float*)d_in[1];   // [3072,1024]
  const float* b1 = (const float*)d_in[2];   // [3072]
  const float* w2 = (const float*)d_in[3];   // [1024,1024]
  const float* b2 = (const float*)d_in[4];   // [1024]
  float* out = (float*)d_out;                // [2,2048,1024] fp32

  char* ws = (char*)d_ws;
  unsigned short* x_bf   = (unsigned short*)(ws);              //  8.39 MB
  unsigned short* w1_bf  = (unsigned short*)(ws + 8388608);    //  6.29 MB
  unsigned short* w2_bf  = (unsigned short*)(ws + 14680064);   //  2.10 MB
  unsigned short* qkv_bf = (unsigned short*)(ws + 16777216);   // 25.17 MB
  unsigned short* at_bf  = (unsigned short*)(ws + 41943040);   //  8.39 MB

  cast_all<<<8192, 256, 0, stream>>>(x, x_bf, w1, w1_bf, w2, w2_bf);

  dim3 g1(3072 / 192, 4096 / 256);   // (16, 16) = 256 blocks, 512 thr
  gemm_qkv<<<g1, 512, 0, stream>>>(x_bf, w1_bf, b1, qkv_bf, 4096, 3072, 1024);

  attn_kernel<<<512, 256, 0, stream>>>(qkv_bf, at_bf);

  dim3 g2(1024 / 64, 4096 / 64);     // (16, 64) = 1024 blocks
  gemm_nt<64, 64, 2, 2, 0><<<g2, 256, 0, stream>>>(at_bf, w2_bf, b2, out, 4096, 1024, 1024);
}